// Round 17
// baseline (1438.640 us; speedup 1.0000x reference)
//
#include <hip/hip_runtime.h>
#include <hip/hip_bf16.h>

#define HIDDEN 256
#define BATCH  64
#define SEQ    2048

// ---------------------------------------------------------------------------
// Phase 1: x_pre[row,h] = bias[h] + sum_d embed[x[row],d] * Wx[h,d]
// (32 rows/block, 256 thr, 16 rows x 2 cols per thread) — proven, unchanged.
// ---------------------------------------------------------------------------
__global__ __launch_bounds__(256, 4)
void xpre_kernel(const int* __restrict__ x,
                 const float* __restrict__ embed,
                 const float* __restrict__ Wx,
                 const float* __restrict__ bias,
                 float* __restrict__ out) {
    const int tid = threadIdx.x;
    const int hh  = tid >> 7;
    const int j2  = tid & 127;
    const long row0 = (long)blockIdx.x * 32;

    __shared__ int toks[32];
    __shared__ __align__(16) float e[32][HIDDEN];

    if (tid < 32) toks[tid] = x[row0 + tid];
    __syncthreads();

    #pragma unroll
    for (int r = 0; r < 32; ++r) {
        e[r][tid] = embed[(long)toks[r] * HIDDEN + tid];
    }
    __syncthreads();

    float acc0[16], acc1[16];
    const float b0 = bias[j2];
    const float b1 = bias[j2 + 128];
    #pragma unroll
    for (int r = 0; r < 16; ++r) { acc0[r] = b0; acc1[r] = b1; }

    const float* wrow0 = Wx + (size_t)j2 * HIDDEN;
    const float* wrow1 = Wx + (size_t)(j2 + 128) * HIDDEN;

    #pragma unroll 2
    for (int d0 = 0; d0 < HIDDEN; d0 += 4) {
        const float4 w0 = *(const float4*)(wrow0 + d0);
        const float4 w1 = *(const float4*)(wrow1 + d0);
        #pragma unroll
        for (int r = 0; r < 16; ++r) {
            const float4 ev = *(const float4*)&e[(hh << 4) + r][d0];
            float a = acc0[r];
            a = fmaf(w0.x, ev.x, a); a = fmaf(w0.y, ev.y, a);
            a = fmaf(w0.z, ev.z, a); a = fmaf(w0.w, ev.w, a);
            acc0[r] = a;
            float c = acc1[r];
            c = fmaf(w1.x, ev.x, c); c = fmaf(w1.y, ev.y, c);
            c = fmaf(w1.z, ev.z, c); c = fmaf(w1.w, ev.w, c);
            acc1[r] = c;
        }
    }

    #pragma unroll
    for (int r = 0; r < 16; ++r) {
        const long orow = (row0 + (hh << 4) + r) * HIDDEN;
        out[orow + j2]       = acc0[r];
        out[orow + j2 + 128] = acc1[r];
    }
}

// ---------------------------------------------------------------------------
// Phase 2: whole-loop-in-asm F32 scan (f16 abandoned: dynamics amplify any
// h quantization -> 4.3e-2..8e-2, threshold 1.5e-2; f32 = only correct path).
// vs R14 (1313 cyc/step, 2 waves/SIMD, ~590 cyc unhidden latency): move to
// 1024 thr = 4 waves/SIMD for latency hiding. Thread (o=tid&15, pc=tid>>4):
// 4 cols {pc+64k}, h-slice h[16o..16o+15]. Weights: 64 f32 at v[64:127]
// (exactly the 128-VGPR/wave cap at 4 waves/EU). 32 pk_fma/step (f32 MAC
// floor 512 cyc/CU), 4-sum merge-reduce (15 instrs vs R13's 29), same
// counted-lgkm MAC interleave, 2-deep x prefetch, vmcnt(2), lgkm-only barrier.
// ---------------------------------------------------------------------------

#define MAC_ASM(RD) \
  "ds_read_b128 v[48:51], " RD "\n\t" \
  "ds_read_b128 v[52:55], " RD " offset:16\n\t" \
  "ds_read_b128 v[56:59], " RD " offset:32\n\t" \
  "ds_read_b128 v[60:63], " RD " offset:48\n\t" \
  "s_waitcnt lgkmcnt(3)\n\t" \
  "v_pk_mul_f32 v[40:41], v[64:65], v[48:49]\n\t" \
  "v_pk_mul_f32 v[42:43], v[80:81], v[48:49]\n\t" \
  "v_pk_mul_f32 v[44:45], v[96:97], v[48:49]\n\t" \
  "v_pk_mul_f32 v[46:47], v[112:113], v[48:49]\n\t" \
  "v_pk_fma_f32 v[40:41], v[66:67], v[50:51], v[40:41]\n\t" \
  "v_pk_fma_f32 v[42:43], v[82:83], v[50:51], v[42:43]\n\t" \
  "v_pk_fma_f32 v[44:45], v[98:99], v[50:51], v[44:45]\n\t" \
  "v_pk_fma_f32 v[46:47], v[114:115], v[50:51], v[46:47]\n\t" \
  "s_waitcnt lgkmcnt(2)\n\t" \
  "v_pk_fma_f32 v[40:41], v[68:69], v[52:53], v[40:41]\n\t" \
  "v_pk_fma_f32 v[42:43], v[84:85], v[52:53], v[42:43]\n\t" \
  "v_pk_fma_f32 v[44:45], v[100:101], v[52:53], v[44:45]\n\t" \
  "v_pk_fma_f32 v[46:47], v[116:117], v[52:53], v[46:47]\n\t" \
  "v_pk_fma_f32 v[40:41], v[70:71], v[54:55], v[40:41]\n\t" \
  "v_pk_fma_f32 v[42:43], v[86:87], v[54:55], v[42:43]\n\t" \
  "v_pk_fma_f32 v[44:45], v[102:103], v[54:55], v[44:45]\n\t" \
  "v_pk_fma_f32 v[46:47], v[118:119], v[54:55], v[46:47]\n\t" \
  "s_waitcnt lgkmcnt(1)\n\t" \
  "v_pk_fma_f32 v[40:41], v[72:73], v[56:57], v[40:41]\n\t" \
  "v_pk_fma_f32 v[42:43], v[88:89], v[56:57], v[42:43]\n\t" \
  "v_pk_fma_f32 v[44:45], v[104:105], v[56:57], v[44:45]\n\t" \
  "v_pk_fma_f32 v[46:47], v[120:121], v[56:57], v[46:47]\n\t" \
  "v_pk_fma_f32 v[40:41], v[74:75], v[58:59], v[40:41]\n\t" \
  "v_pk_fma_f32 v[42:43], v[90:91], v[58:59], v[42:43]\n\t" \
  "v_pk_fma_f32 v[44:45], v[106:107], v[58:59], v[44:45]\n\t" \
  "v_pk_fma_f32 v[46:47], v[122:123], v[58:59], v[46:47]\n\t" \
  "s_waitcnt lgkmcnt(0)\n\t" \
  "v_pk_fma_f32 v[40:41], v[76:77], v[60:61], v[40:41]\n\t" \
  "v_pk_fma_f32 v[42:43], v[92:93], v[60:61], v[42:43]\n\t" \
  "v_pk_fma_f32 v[44:45], v[108:109], v[60:61], v[44:45]\n\t" \
  "v_pk_fma_f32 v[46:47], v[124:125], v[60:61], v[46:47]\n\t" \
  "v_pk_fma_f32 v[40:41], v[78:79], v[62:63], v[40:41]\n\t" \
  "v_pk_fma_f32 v[42:43], v[94:95], v[62:63], v[42:43]\n\t" \
  "v_pk_fma_f32 v[44:45], v[110:111], v[62:63], v[44:45]\n\t" \
  "v_pk_fma_f32 v[46:47], v[126:127], v[62:63], v[46:47]\n\t" \
  "v_add_f32 v48, v40, v41\n\t" \
  "v_add_f32 v49, v42, v43\n\t" \
  "v_add_f32 v50, v44, v45\n\t" \
  "v_add_f32 v51, v46, v47\n\t"

// 4-sum merge-reduce over 16 o-lanes; every lane ends with col (o&3)'s total
// in v48. Stages: xor8 (ror8 self-add), merge-bit0 + xor1, merge-bit1 + xor2,
// final self-add ror4 (== xor4: value depends only on o&3 and bit2 by then).
#define RED_ASM \
  "v_add_f32_dpp v48, v48, v48 row_ror:8 row_mask:0xf bank_mask:0xf\n\t" \
  "v_add_f32_dpp v49, v49, v49 row_ror:8 row_mask:0xf bank_mask:0xf\n\t" \
  "v_add_f32_dpp v50, v50, v50 row_ror:8 row_mask:0xf bank_mask:0xf\n\t" \
  "v_add_f32_dpp v51, v51, v51 row_ror:8 row_mask:0xf bank_mask:0xf\n\t" \
  "v_cndmask_b32 v52, v49, v48, s[24:25]\n\t" \
  "v_cndmask_b32 v53, v51, v50, s[24:25]\n\t" \
  "v_cndmask_b32 v48, v48, v49, s[24:25]\n\t" \
  "v_cndmask_b32 v50, v50, v51, s[24:25]\n\t" \
  "v_add_f32_dpp v48, v52, v48 quad_perm:[1,0,3,2] row_mask:0xf bank_mask:0xf\n\t" \
  "v_add_f32_dpp v50, v53, v50 quad_perm:[1,0,3,2] row_mask:0xf bank_mask:0xf\n\t" \
  "v_cndmask_b32 v52, v50, v48, s[26:27]\n\t" \
  "v_cndmask_b32 v48, v48, v50, s[26:27]\n\t" \
  "s_nop 1\n\t" \
  "v_add_f32_dpp v48, v52, v48 quad_perm:[2,3,0,1] row_mask:0xf bank_mask:0xf\n\t" \
  "s_nop 1\n\t" \
  "v_add_f32_dpp v48, v48, v48 row_ror:4 row_mask:0xf bank_mask:0xf\n\t"

// finish: counted vmcnt, xp add, tanh, exec-masked ds_write + global store,
// prefetch-reg rotate, pointer advance, lgkm-only barrier (store ptr 2 ahead).
#define FIN_ASM(WR, XP, MD, MS) \
  "s_waitcnt vmcnt(2)\n\t" \
  "v_add_f32 v57, v48, " XP "\n\t" \
  "v_mul_f32 v54, 0x4038AA3B, v57\n\t" \
  "v_exp_f32 v55, v54\n\t" \
  "s_nop 0\n\t" \
  "v_add_f32 v55, 1.0, v55\n\t" \
  "v_rcp_f32 v56, v55\n\t" \
  "s_nop 0\n\t" \
  "v_fma_f32 v57, -2.0, v56, v34\n\t" \
  "s_and_saveexec_b64 s[20:21], s[22:23]\n\t" \
  "ds_write_b32 " WR ", v57\n\t" \
  "global_store_dword v[32:33], v57, off offset:-2048\n\t" \
  "s_mov_b64 exec, s[20:21]\n\t" \
  "v_mov_b32 " MD ", " MS "\n\t" \
  "v_add_co_u32 v32, vcc, 0x400, v32\n\t" \
  "v_addc_co_u32 v33, vcc, v33, 0, vcc\n\t" \
  "s_waitcnt lgkmcnt(0)\n\t" \
  "s_barrier\n\t"

__global__ __attribute__((amdgpu_flat_work_group_size(1024, 1024)))
void rnn_scan_kernel(const float* __restrict__ Wh,
                     float* __restrict__ out) {
    const int tid = threadIdx.x;
    const int o   = tid & 15;    // h-slice index: h[16o..16o+15]
    const int pc  = tid >> 4;    // column group [0,64): cols {pc+64k}
    const int b   = blockIdx.x;

    // f32 h buffers: buf0 @ byte 0, buf1 @ byte 2048; slot(f) = f + 4*(f>>4)
    __shared__ __align__(16) float hraw[1024];
    hraw[tid] = 0.0f;            // zeros both buffers (1024 floats total)
    __syncthreads();

    unsigned lbase = (unsigned)(unsigned long long)
                     (__attribute__((address_space(3))) char*)hraw;
    const int col  = pc + 64 * (o & 3);          // writer (o<4) column
    const int slot = col + 4 * (col >> 4);
    const unsigned rda = lbase + 80u * (unsigned)o;           // read buf0
    const unsigned rdb = rda + 2048u;                         // read buf1
    const unsigned wra = lbase + 2048u + 4u * (unsigned)slot; // write buf1
    const unsigned wrb = lbase + 4u * (unsigned)slot;         // write buf0

    const float* xa = out + ((size_t)b * SEQ + 2) * HIDDEN + col; // ptr@row2
    const unsigned xlo = (unsigned)(size_t)xa;
    const unsigned xhi = (unsigned)((size_t)xa >> 32);

    const float* wp0 = Wh + (size_t)(pc +   0) * HIDDEN + 16 * o;
    const float* wp1 = Wh + (size_t)(pc +  64) * HIDDEN + 16 * o;
    const float* wp2 = Wh + (size_t)(pc + 128) * HIDDEN + 16 * o;
    const float* wp3 = Wh + (size_t)(pc + 192) * HIDDEN + 16 * o;

    asm volatile(
        // ---- prologue: weights -> v[64:127] (16 consecutive floats each:
        // byte offsets 0/16/32/48), ptr/consts, xp prefetch, lane masks ----
        "v_mov_b32 v32, %[xlo]\n\t"
        "v_mov_b32 v33, %[xhi]\n\t"
        "v_mov_b32 v34, 1.0\n\t"
        "global_load_dwordx4 v[64:67],   %[wp0], off\n\t"
        "global_load_dwordx4 v[68:71],   %[wp0], off offset:16\n\t"
        "global_load_dwordx4 v[72:75],   %[wp0], off offset:32\n\t"
        "global_load_dwordx4 v[76:79],   %[wp0], off offset:48\n\t"
        "global_load_dwordx4 v[80:83],   %[wp1], off\n\t"
        "global_load_dwordx4 v[84:87],   %[wp1], off offset:16\n\t"
        "global_load_dwordx4 v[88:91],   %[wp1], off offset:32\n\t"
        "global_load_dwordx4 v[92:95],   %[wp1], off offset:48\n\t"
        "global_load_dwordx4 v[96:99],   %[wp2], off\n\t"
        "global_load_dwordx4 v[100:103], %[wp2], off offset:16\n\t"
        "global_load_dwordx4 v[104:107], %[wp2], off offset:32\n\t"
        "global_load_dwordx4 v[108:111], %[wp2], off offset:48\n\t"
        "global_load_dwordx4 v[112:115], %[wp3], off\n\t"
        "global_load_dwordx4 v[116:119], %[wp3], off offset:16\n\t"
        "global_load_dwordx4 v[120:123], %[wp3], off offset:32\n\t"
        "global_load_dwordx4 v[124:127], %[wp3], off offset:48\n\t"
        "global_load_dword v36, v[32:33], off offset:-2048\n\t"   // row 0
        "global_load_dword v39, v[32:33], off offset:-1024\n\t"   // row 1
        "v_and_b32 v48, 1, %[vo]\n\t"
        "v_cmp_eq_u32 s[24:25], 1, v48\n\t"
        "v_and_b32 v48, 2, %[vo]\n\t"
        "v_cmp_eq_u32 s[26:27], 2, v48\n\t"
        "v_cmp_gt_u32 s[22:23], 4, %[vo]\n\t"
        "s_movk_i32 s30, 0x400\n\t"
        "s_waitcnt vmcnt(0)\n\t"
        // ---- main loop: 1024 iterations x 2 steps; ptr = row t+2 at half A
        "RNN%=:\n\t"
        "s_cmp_eq_u32 s30, 1\n\t"
        "s_cbranch_scc1 LDA%=\n\t"
        "global_load_dword v38, v[32:33], off\n\t"
        "s_branch LCA%=\n\t"
        "LDA%=:\n\t"
        "global_load_dword v38, v[32:33], off offset:-1024\n\t"
        "LCA%=:\n\t"
        MAC_ASM("%[rda]")
        RED_ASM
        FIN_ASM("%[wra]", "v36", "v37", "v39")
        "s_cmp_eq_u32 s30, 1\n\t"
        "s_cbranch_scc1 LDB%=\n\t"
        "global_load_dword v39, v[32:33], off\n\t"
        "s_branch LCB%=\n\t"
        "LDB%=:\n\t"
        "global_load_dword v39, v[32:33], off offset:-2048\n\t"
        "LCB%=:\n\t"
        MAC_ASM("%[rdb]")
        RED_ASM
        FIN_ASM("%[wrb]", "v37", "v36", "v38")
        "s_sub_u32 s30, s30, 1\n\t"
        "s_cmp_lg_u32 s30, 0\n\t"
        "s_cbranch_scc1 RNN%=\n\t"
        "s_waitcnt vmcnt(0) lgkmcnt(0)\n\t"
        :
        : [wp0] "v"(wp0), [wp1] "v"(wp1), [wp2] "v"(wp2), [wp3] "v"(wp3),
          [xlo] "v"(xlo), [xhi] "v"(xhi),
          [rda] "v"(rda), [rdb] "v"(rdb), [wra] "v"(wra), [wrb] "v"(wrb),
          [vo]  "v"(o)
        : "memory", "vcc", "scc",
          "s20","s21","s22","s23","s24","s25","s26","s27","s28","s29","s30",
          "v32","v33","v34","v35","v36","v37","v38","v39",
          "v40","v41","v42","v43","v44","v45","v46","v47",
          "v48","v49","v50","v51","v52","v53","v54","v55",
          "v56","v57","v58","v59","v60","v61","v62","v63",
          "v64","v65","v66","v67","v68","v69","v70","v71",
          "v72","v73","v74","v75","v76","v77","v78","v79",
          "v80","v81","v82","v83","v84","v85","v86","v87",
          "v88","v89","v90","v91","v92","v93","v94","v95",
          "v96","v97","v98","v99","v100","v101","v102","v103",
          "v104","v105","v106","v107","v108","v109","v110","v111",
          "v112","v113","v114","v115","v116","v117","v118","v119",
          "v120","v121","v122","v123","v124","v125","v126","v127");
}

extern "C" void kernel_launch(void* const* d_in, const int* in_sizes, int n_in,
                              void* d_out, int out_size, void* d_ws, size_t ws_size,
                              hipStream_t stream) {
    const int*   x     = (const int*)d_in[0];
    const float* embed = (const float*)d_in[1];
    const float* Wx    = (const float*)d_in[2];
    const float* Wxb   = (const float*)d_in[3];
    const float* Wh    = (const float*)d_in[4];
    float* out = (float*)d_out;

    const int nrows = BATCH * SEQ;                  // 131072, 32 rows/block
    xpre_kernel<<<nrows / 32, 256, 0, stream>>>(x, embed, Wx, Wxb, out);

    rnn_scan_kernel<<<BATCH, 1024, 0, stream>>>(Wh, out);
}